// Round 8
// baseline (316.565 us; speedup 1.0000x reference)
//
#include <hip/hip_runtime.h>
#include <hip/hip_bf16.h>

// MHA block: B=2, S=2048, D=1024, H=16, Dk=64. fp32 inputs (runtime-detected),
// bf16 MFMA with fp32 accumulation.
// Fast path (ws >= 64MiB+16): convert (fused dtype-detect) -> BK=64 GEMMs
// (global_load_lds + XOR chunk swizzle; XCD-local grid order) -> attn -> proj.
// Attention v5: ZERO LDS, ZERO barriers. Each wave loads K/V fragments
// directly global->VGPR (key permutation baked into per-lane addresses),
// register double-buffered across tiles so loads stay in flight during MFMA
// (AITER-style pipeline, waitcnt never drains to 0). XCD swizzle: all q-tiles
// of one (b,h) land on one XCD -> K/V stay hot in that L2.
// S^T=K.Q^T so P exits QK^T in PV A-fragment layout; denom via MFMA-ones.
// Q pre-scaled by 0.125*log2(e) -> raw v_exp_f32.

typedef __bf16 bf16_t;
typedef bf16_t bf16x8 __attribute__((ext_vector_type(8)));
typedef bf16_t bf16x4 __attribute__((ext_vector_type(4)));
typedef float f32x4 __attribute__((ext_vector_type(4)));

#define D_MODEL 1024
#define SEQ 2048
#define NH 16
#define DK 64

#define QSCALE 0.18033688011112042f  // 0.125 * log2(e)

__device__ __forceinline__ float fast_exp2(float x) {
#if __has_builtin(__builtin_amdgcn_exp2f)
  return __builtin_amdgcn_exp2f(x);
#else
  return exp2f(x);
#endif
}

// load 8 consecutive elements as bf16x8, converting from fp32 if f32 != 0.
__device__ __forceinline__ bf16x8 load8(const void* __restrict__ base,
                                        size_t idx, int f32) {
  if (f32) {
    f32x4 a = *(const f32x4*)((const float*)base + idx);
    f32x4 b = *(const f32x4*)((const float*)base + idx + 4);
    bf16x8 r;
    r[0] = (bf16_t)a[0]; r[1] = (bf16_t)a[1];
    r[2] = (bf16_t)a[2]; r[3] = (bf16_t)a[3];
    r[4] = (bf16_t)b[0]; r[5] = (bf16_t)b[1];
    r[6] = (bf16_t)b[2]; r[7] = (bf16_t)b[3];
    return r;
  }
  return *(const bf16x8*)((const bf16_t*)base + idx);
}

// ---------------------------------------------------------------------------
// standalone detector (fallback path only)
// ---------------------------------------------------------------------------
__global__ __launch_bounds__(256) void detect_kernel(const float* __restrict__ q,
                                                     int* __restrict__ flag) {
  __shared__ int total;
  if (threadIdx.x == 0) total = 0;
  __syncthreads();
  f32x4 v = ((const f32x4*)q)[threadIdx.x];
  int cnt = 0;
#pragma unroll
  for (int j = 0; j < 4; ++j) {
    unsigned u = __float_as_uint(v[j]);
    unsigned e = (u >> 23) & 0xffu;
    cnt += (e >= 0x70u && e <= 0x8fu) ? 1 : 0;
  }
  atomicAdd(&total, cnt);
  __syncthreads();
  if (threadIdx.x == 0) *flag = (total >= 512) ? 1 : 0;
}

// ---------------------------------------------------------------------------
// convert pass with fused per-block dtype detection.
// ---------------------------------------------------------------------------
__global__ __launch_bounds__(256) void convert_kernel(
    const void* __restrict__ s0, const void* __restrict__ s1,
    const void* __restrict__ s2, const void* __restrict__ s3,
    const void* __restrict__ s4, const void* __restrict__ s5,
    const void* __restrict__ s6, bf16_t* __restrict__ dst,
    int* __restrict__ flag_out) {
  const int t = blockIdx.y;
  const void* src = (t == 0) ? s0 : (t == 1) ? s1 : (t == 2) ? s2
                   : (t == 3) ? s3 : (t == 4) ? s4 : (t == 5) ? s5 : s6;
  const size_t sz = (t < 3) ? ((size_t)1 << 22) : ((size_t)1 << 20);
  const size_t off =
      (t < 3) ? ((size_t)t << 22) : ((size_t)12 << 20) + ((size_t)(t - 3) << 20);
  const size_t i = ((size_t)blockIdx.x * 256 + threadIdx.x) * 8;
  if (i >= sz) return;

  __shared__ int total;
  if (threadIdx.x == 0) total = 0;
  __syncthreads();
  const size_t wi = (i >> 1) & ~(size_t)3;
  f32x4 smp = *(const f32x4*)((const float*)src + wi);
  int cnt = 0;
#pragma unroll
  for (int j = 0; j < 4; ++j) {
    unsigned u = __float_as_uint(smp[j]);
    unsigned e = (u >> 23) & 0xffu;
    cnt += (e >= 0x70u && e <= 0x8fu) ? 1 : 0;
  }
  atomicAdd(&total, cnt);
  __syncthreads();
  const int f32 = (total >= 512) ? 1 : 0;
  if (t == 0 && blockIdx.x == 0 && threadIdx.x == 0) *flag_out = f32;

  *(bf16x8*)&dst[off + i] = load8(src, i, f32);
}

// ---------------------------------------------------------------------------
// async global(bf16)->LDS, 16B per lane; LDS dest = wave-uniform base+lane*16.
// ---------------------------------------------------------------------------
__device__ __forceinline__ void gload16(const bf16_t* g, bf16_t* l) {
  __builtin_amdgcn_global_load_lds(
      (const __attribute__((address_space(1))) unsigned int*)g,
      (__attribute__((address_space(3))) unsigned int*)l, 16, 0, 0);
}

// ---------------------------------------------------------------------------
// shared epilogue for C = A . W^T GEMMs (tile 128 x BN).
// ---------------------------------------------------------------------------
template <int NT>
__device__ __forceinline__ void gemm_epilogue(f32x4 acc[4][NT], void* out,
                                              int mode, int f32out, float osc,
                                              int m0, int n0, int wm, int wn,
                                              int l16, int quad) {
#pragma unroll
  for (int mt = 0; mt < 4; ++mt) {
#pragma unroll
    for (int nt = 0; nt < NT; ++nt) {
      const int mbase = m0 + wm + mt * 16 + quad * 4;
      const int n = n0 + wn + nt * 16 + l16;
      const int b = mbase >> 11;
      const int sbase = mbase & 2047;
      if (mode == 2) {
        const int h = n >> 6, d = n & 63;
        bf16x4 pk;
#pragma unroll
        for (int r = 0; r < 4; ++r) pk[r] = (bf16_t)acc[mt][nt][r];
        *(bf16x4*)&((bf16_t*)out)[((size_t)(b * NH + h) * DK + d) * SEQ +
                                  sbase] = pk;
      } else if (mode == 3) {
        if (f32out) {
#pragma unroll
          for (int r = 0; r < 4; ++r)
            ((float*)out)[(size_t)(mbase + r) * 1024 + n] = acc[mt][nt][r];
        } else {
#pragma unroll
          for (int r = 0; r < 4; ++r)
            ((bf16_t*)out)[(size_t)(mbase + r) * 1024 + n] =
                (bf16_t)acc[mt][nt][r];
        }
      } else {
        const int h = n >> 6, d = n & 63;
#pragma unroll
        for (int r = 0; r < 4; ++r)
          ((bf16_t*)out)[((size_t)(b * NH + h) * SEQ + (sbase + r)) * DK + d] =
              (bf16_t)(acc[mt][nt][r] * osc);
      }
    }
  }
}

// ---------------------------------------------------------------------------
// FAST GEMM: BK=64, global_load_lds staging with XOR chunk swizzle.
// m0/n0 passed in so callers pick grid order (m-tiles in fast dim -> all
// n-siblings sharing an A-tile land on one XCD: A fetched once per XCD).
// ---------------------------------------------------------------------------
template <int BN>
__device__ __forceinline__ void gemm_fast_body(const bf16_t* __restrict__ A,
                                               const bf16_t* __restrict__ W,
                                               void* __restrict__ out, int mode,
                                               int f32out, float osc, int m0,
                                               int n0) {
  constexpr int NT = BN / 32;
  constexpr int BR = BN / 32;
  __shared__ alignas(16) bf16_t lA[128 * 64];
  __shared__ alignas(16) bf16_t lB[BN * 64];
  const int tid = threadIdx.x;
  const int ln = tid & 63;
  const int wave = tid >> 6;
  const int l16 = ln & 15;
  const int quad = ln >> 4;
  const int wm = (wave & 1) * 64;
  const int wn = (wave >> 1) * (BN / 2);
  f32x4 acc[4][NT] = {};

  const int srow = ln >> 3;
  const int schunk = ((ln & 7) ^ (ln >> 3)) * 8;
  const int pc0 = (quad ^ (l16 & 7)) * 8;
  const int pc1 = ((quad + 4) ^ (l16 & 7)) * 8;

  for (int k0 = 0; k0 < 1024; k0 += 64) {
    __syncthreads();
#pragma unroll
    for (int i = 0; i < 4; ++i)
      gload16(&A[(size_t)(m0 + i * 32 + wave * 8 + srow) * 1024 + k0 + schunk],
              &lA[i * 2048 + wave * 512]);
#pragma unroll
    for (int i = 0; i < BR; ++i)
      gload16(&W[(size_t)(n0 + i * 32 + wave * 8 + srow) * 1024 + k0 + schunk],
              &lB[i * 2048 + wave * 512]);
    __syncthreads();

    bf16x8 af0[4], af1[4], bf0[NT], bf1[NT];
#pragma unroll
    for (int mt = 0; mt < 4; ++mt) {
      af0[mt] = *(bf16x8*)&lA[(wm + mt * 16 + l16) * 64 + pc0];
      af1[mt] = *(bf16x8*)&lA[(wm + mt * 16 + l16) * 64 + pc1];
    }
#pragma unroll
    for (int nt = 0; nt < NT; ++nt) {
      bf0[nt] = *(bf16x8*)&lB[(wn + nt * 16 + l16) * 64 + pc0];
      bf1[nt] = *(bf16x8*)&lB[(wn + nt * 16 + l16) * 64 + pc1];
    }
#pragma unroll
    for (int mt = 0; mt < 4; ++mt)
#pragma unroll
      for (int nt = 0; nt < NT; ++nt) {
        acc[mt][nt] = __builtin_amdgcn_mfma_f32_16x16x32_bf16(
            af0[mt], bf0[nt], acc[mt][nt], 0, 0, 0);
        acc[mt][nt] = __builtin_amdgcn_mfma_f32_16x16x32_bf16(
            af1[mt], bf1[nt], acc[mt][nt], 0, 0, 0);
      }
  }
  gemm_epilogue<NT>(acc, out, mode, f32out, osc, m0, n0, wm, wn, l16, quad);
}

__global__ __launch_bounds__(256) void qkv_fast(
    const bf16_t* __restrict__ qb, const bf16_t* __restrict__ kb,
    const bf16_t* __restrict__ vb, const bf16_t* __restrict__ wqb,
    const bf16_t* __restrict__ wkb, const bf16_t* __restrict__ wvb,
    bf16_t* __restrict__ qo, bf16_t* __restrict__ ko, bf16_t* __restrict__ vo) {
  const int z = blockIdx.z;
  const bf16_t* A = (z == 0) ? qb : (z == 1) ? kb : vb;
  const bf16_t* W = (z == 0) ? wqb : (z == 1) ? wkb : wvb;
  bf16_t* O = (z == 0) ? qo : (z == 1) ? ko : vo;
  gemm_fast_body<128>(A, W, O, (z == 2) ? 2 : 0, 0, (z == 0) ? QSCALE : 1.0f,
                      blockIdx.x * 128, blockIdx.y * 128);
}

__global__ __launch_bounds__(256) void outproj_fast(
    const bf16_t* __restrict__ X, const bf16_t* __restrict__ wob,
    void* __restrict__ out, const int* __restrict__ flag) {
  gemm_fast_body<64>(X, wob, out, 3, *flag, 1.0f, blockIdx.x * 128,
                     blockIdx.y * 64);
}

// ---------------------------------------------------------------------------
// FALLBACK GEMM: fused fp32->bf16 staging through VGPRs (BK=32).
// ---------------------------------------------------------------------------
__device__ __forceinline__ void gemm_bt_body(const void* __restrict__ A,
                                             const void* __restrict__ W,
                                             void* __restrict__ out, int mode,
                                             int aRaw, float osc,
                                             const int* __restrict__ flag) {
  __shared__ alignas(16) bf16_t lA[128 * 32];
  __shared__ alignas(16) bf16_t lB[128 * 32];
  const int f = *flag;
  const int af32 = aRaw ? f : 0;

  const int tid = threadIdx.x;
  const int lane = tid & 63;
  const int wave = tid >> 6;
  const int l16 = lane & 15;
  const int quad = lane >> 4;
  const int m0 = blockIdx.y * 128;
  const int n0 = blockIdx.x * 128;
  const int wm = (wave & 1) * 64;
  const int wn = (wave >> 1) * 64;

  f32x4 acc[4][4] = {};
  const int r0 = tid >> 2;
  const int kc = (tid & 3) * 8;

  for (int k0 = 0; k0 < 1024; k0 += 32) {
    __syncthreads();
    *(bf16x8*)&lA[r0 * 32 + kc] =
        load8(A, (size_t)(m0 + r0) * 1024 + k0 + kc, af32);
    *(bf16x8*)&lA[(r0 + 64) * 32 + kc] =
        load8(A, (size_t)(m0 + r0 + 64) * 1024 + k0 + kc, af32);
    *(bf16x8*)&lB[r0 * 32 + kc] =
        load8(W, (size_t)(n0 + r0) * 1024 + k0 + kc, f);
    *(bf16x8*)&lB[(r0 + 64) * 32 + kc] =
        load8(W, (size_t)(n0 + r0 + 64) * 1024 + k0 + kc, f);
    __syncthreads();

    bf16x8 af[4], bfr[4];
#pragma unroll
    for (int mt = 0; mt < 4; ++mt)
      af[mt] = *(bf16x8*)&lA[(wm + mt * 16 + l16) * 32 + quad * 8];
#pragma unroll
    for (int nt = 0; nt < 4; ++nt)
      bfr[nt] = *(bf16x8*)&lB[(wn + nt * 16 + l16) * 32 + quad * 8];
#pragma unroll
    for (int mt = 0; mt < 4; ++mt)
#pragma unroll
      for (int nt = 0; nt < 4; ++nt)
        acc[mt][nt] = __builtin_amdgcn_mfma_f32_16x16x32_bf16(
            af[mt], bfr[nt], acc[mt][nt], 0, 0, 0);
  }
  gemm_epilogue<4>(acc, out, mode, (mode == 3) ? f : 0, osc, m0, n0, wm, wn,
                   l16, quad);
}

__global__ __launch_bounds__(256) void qkv_kernel(
    const void* __restrict__ q, const void* __restrict__ k,
    const void* __restrict__ v, const void* __restrict__ wq,
    const void* __restrict__ wk, const void* __restrict__ wv,
    bf16_t* __restrict__ qo, bf16_t* __restrict__ ko, bf16_t* __restrict__ vo,
    const int* __restrict__ flag) {
  const int z = blockIdx.z;
  const void* A = (z == 0) ? q : (z == 1) ? k : v;
  const void* W = (z == 0) ? wq : (z == 1) ? wk : wv;
  bf16_t* O = (z == 0) ? qo : (z == 1) ? ko : vo;
  gemm_bt_body(A, W, O, (z == 2) ? 2 : 0, 1, (z == 0) ? QSCALE : 1.0f, flag);
}

__global__ __launch_bounds__(256) void outproj_kernel(
    const bf16_t* __restrict__ X, const void* __restrict__ wo,
    void* __restrict__ out, const int* __restrict__ flag) {
  gemm_bt_body(X, wo, out, 3, 0, 1.0f, flag);
}

// ---------------------------------------------------------------------------
// Attention v5: 1024 blocks x 128 threads; block = (b,h) x 64 q-rows; wave =
// 32 q-rows, fully independent (no LDS, no barriers). Per tile (32 keys) each
// wave loads 4 K-frags + 4 V-frags straight to VGPRs; key permutation
// pkey(r)=((r>>2)&3)*8+(r>>4)*4+(r&3) baked into lane addresses so the
// C-layout scores land exactly in PV A-fragment slots. Register double-buffer
// (sets A/B) keeps next tile's 8 loads in flight under current tile's MFMAs.
// XCD swizzle: bh = bx & 31 -> all q-tiles of a head on one XCD's L2.
// ---------------------------------------------------------------------------
#define ATTN_LOAD(S, TILE)                                   \
  {                                                          \
    const size_t ko = (size_t)(TILE) * 2048;                 \
    const size_t vo = (size_t)(TILE) * 32;                   \
    kf00##S = *(const bf16x8*)(kb00 + ko);                   \
    kf01##S = *(const bf16x8*)(kb01 + ko);                   \
    kf10##S = *(const bf16x8*)(kb10 + ko);                   \
    kf11##S = *(const bf16x8*)(kb11 + ko);                   \
    vf0##S = *(const bf16x8*)(vb0 + vo);                     \
    vf1##S = *(const bf16x8*)(vb1 + vo);                     \
    vf2##S = *(const bf16x8*)(vb2 + vo);                     \
    vf3##S = *(const bf16x8*)(vb3 + vo);                     \
  }

#define ATTN_COMPUTE(S)                                                       \
  {                                                                           \
    float pv0[8], pv1[8];                                                     \
    {                                                                         \
      f32x4 s0 = {0.f, 0.f, 0.f, 0.f}, s1 = {0.f, 0.f, 0.f, 0.f};            \
      s0 = __builtin_amdgcn_mfma_f32_16x16x32_bf16(kf00##S, qf00, s0, 0, 0, 0); \
      s0 = __builtin_amdgcn_mfma_f32_16x16x32_bf16(kf01##S, qf01, s0, 0, 0, 0); \
      s1 = __builtin_amdgcn_mfma_f32_16x16x32_bf16(kf00##S, qf10, s1, 0, 0, 0); \
      s1 = __builtin_amdgcn_mfma_f32_16x16x32_bf16(kf01##S, qf11, s1, 0, 0, 0); \
      _Pragma("unroll") for (int r = 0; r < 4; ++r) {                         \
        pv0[r] = fast_exp2(s0[r]);                                            \
        pv1[r] = fast_exp2(s1[r]);                                            \
      }                                                                       \
    }                                                                         \
    {                                                                         \
      f32x4 s0 = {0.f, 0.f, 0.f, 0.f}, s1 = {0.f, 0.f, 0.f, 0.f};            \
      s0 = __builtin_amdgcn_mfma_f32_16x16x32_bf16(kf10##S, qf00, s0, 0, 0, 0); \
      s0 = __builtin_amdgcn_mfma_f32_16x16x32_bf16(kf11##S, qf01, s0, 0, 0, 0); \
      s1 = __builtin_amdgcn_mfma_f32_16x16x32_bf16(kf10##S, qf10, s1, 0, 0, 0); \
      s1 = __builtin_amdgcn_mfma_f32_16x16x32_bf16(kf11##S, qf11, s1, 0, 0, 0); \
      _Pragma("unroll") for (int r = 0; r < 4; ++r) {                         \
        pv0[4 + r] = fast_exp2(s0[r]);                                        \
        pv1[4 + r] = fast_exp2(s1[r]);                                        \
      }                                                                       \
    }                                                                         \
    bf16x8 pf0, pf1;                                                          \
    _Pragma("unroll") for (int j = 0; j < 8; ++j) {                           \
      pf0[j] = (bf16_t)pv0[j];                                                \
      pf1[j] = (bf16_t)pv1[j];                                                \
    }                                                                         \
    sacc0 = __builtin_amdgcn_mfma_f32_16x16x32_bf16(pf0, ones, sacc0, 0, 0, 0); \
    sacc1 = __builtin_amdgcn_mfma_f32_16x16x32_bf16(pf1, ones, sacc1, 0, 0, 0); \
    xacc0[0] = __builtin_amdgcn_mfma_f32_16x16x32_bf16(pf0, vf0##S, xacc0[0], 0, 0, 0); \
    xacc1[0] = __builtin_amdgcn_mfma_f32_16x16x32_bf16(pf1, vf0##S, xacc1[0], 0, 0, 0); \
    xacc0[1] = __builtin_amdgcn_mfma_f32_16x16x32_bf16(pf0, vf1##S, xacc0[1], 0, 0, 0); \
    xacc1[1] = __builtin_amdgcn_mfma_f32_16x16x32_bf16(pf1, vf1##S, xacc1[1], 0, 0, 0); \
    xacc0[2] = __builtin_amdgcn_mfma_f32_16x16x32_bf16(pf0, vf2##S, xacc0[2], 0, 0, 0); \
    xacc1[2] = __builtin_amdgcn_mfma_f32_16x16x32_bf16(pf1, vf2##S, xacc1[2], 0, 0, 0); \
    xacc0[3] = __builtin_amdgcn_mfma_f32_16x16x32_bf16(pf0, vf3##S, xacc0[3], 0, 0, 0); \
    xacc1[3] = __builtin_amdgcn_mfma_f32_16x16x32_bf16(pf1, vf3##S, xacc1[3], 0, 0, 0); \
  }

__global__ __launch_bounds__(128, 2) void attn_kernel(
    const bf16_t* __restrict__ qws, const bf16_t* __restrict__ kws,
    const bf16_t* __restrict__ vtws, bf16_t* __restrict__ xws) {
  const int tid = threadIdx.x;
  const int lane = tid & 63;
  const int wave = tid >> 6;  // 0/1
  const int l16 = lane & 15;
  const int quad = lane >> 4;
  const int bx = blockIdx.x;
  const int bh = bx & 31;  // XCD-local: same head -> same XCD (bx%8 fixed)
  const int qt = bx >> 5;  // 64-row q block
  const int b = bh >> 4, h = bh & 15;

  const bf16_t* qp = qws + (size_t)bh * SEQ * DK;
  const bf16_t* kp = kws + (size_t)bh * SEQ * DK;
  const bf16_t* vp = vtws + (size_t)bh * DK * SEQ;
  const int qrow = qt * 64 + wave * 32;

  // Q fragments (held all loop)
  const bf16x8 qf00 = *(const bf16x8*)&qp[(size_t)(qrow + l16) * DK + quad * 8];
  const bf16x8 qf01 =
      *(const bf16x8*)&qp[(size_t)(qrow + l16) * DK + 32 + quad * 8];
  const bf16x8 qf10 =
      *(const bf16x8*)&qp[(size_t)(qrow + 16 + l16) * DK + quad * 8];
  const bf16x8 qf11 =
      *(const bf16x8*)&qp[(size_t)(qrow + 16 + l16) * DK + 32 + quad * 8];

  // K base pointers: A-operand m=l16 of subtile nt maps to key pkey(nt*16+l16)
  const int key0 = ((l16 >> 2) & 3) * 8 + (l16 & 3);  // pkey(l16)
  const bf16_t* kb00 = kp + (size_t)key0 * DK + quad * 8;
  const bf16_t* kb01 = kb00 + 32;
  const bf16_t* kb10 = kb00 + 4 * DK;  // pkey(16+l16) = key0+4
  const bf16_t* kb11 = kb10 + 32;

  // V^T base pointers: row d = ntd*16+l16, chunk quad over keys
  const bf16_t* vb0 = vp + (size_t)(l16)*SEQ + quad * 8;
  const bf16_t* vb1 = vp + (size_t)(16 + l16) * SEQ + quad * 8;
  const bf16_t* vb2 = vp + (size_t)(32 + l16) * SEQ + quad * 8;
  const bf16_t* vb3 = vp + (size_t)(48 + l16) * SEQ + quad * 8;

  bf16x8 ones;
#pragma unroll
  for (int j = 0; j < 8; ++j) ones[j] = (bf16_t)1.0f;

  f32x4 xacc0[4] = {}, xacc1[4] = {};
  f32x4 sacc0 = {0.f, 0.f, 0.f, 0.f};
  f32x4 sacc1 = {0.f, 0.f, 0.f, 0.f};

  bf16x8 kf00A, kf01A, kf10A, kf11A, vf0A, vf1A, vf2A, vf3A;
  bf16x8 kf00B, kf01B, kf10B, kf11B, vf0B, vf1B, vf2B, vf3B;

  ATTN_LOAD(A, 0);
  for (int t = 0; t < 62; t += 2) {
    ATTN_LOAD(B, t + 1);
    ATTN_COMPUTE(A);
    ATTN_LOAD(A, t + 2);
    ATTN_COMPUTE(B);
  }
  ATTN_LOAD(B, 63);
  ATTN_COMPUTE(A);  // tile 62
  ATTN_COMPUTE(B);  // tile 63

  float li0[4], li1[4];
#pragma unroll
  for (int r = 0; r < 4; ++r) {
    li0[r] = 1.0f / sacc0[r];
    li1[r] = 1.0f / sacc1[r];
  }

#pragma unroll
  for (int ntd = 0; ntd < 4; ++ntd)
#pragma unroll
    for (int r = 0; r < 4; ++r) {
      const int col = h * DK + ntd * 16 + l16;
      const int s0 = qrow + quad * 4 + r;
      const int s1 = qrow + 16 + quad * 4 + r;
      xws[((size_t)b * SEQ + s0) * D_MODEL + col] =
          (bf16_t)(xacc0[ntd][r] * li0[r]);
      xws[((size_t)b * SEQ + s1) * D_MODEL + col] =
          (bf16_t)(xacc1[ntd][r] * li1[r]);
    }
}

extern "C" void kernel_launch(void* const* d_in, const int* in_sizes, int n_in,
                              void* d_out, int out_size, void* d_ws,
                              size_t ws_size, hipStream_t stream) {
  char* base = (char*)d_ws;
  int* flag = (int*)base;
  bf16_t* wsb = (bf16_t*)(base + 16);
  const size_t M4 = (size_t)4 * 1024 * 1024;
  const size_t M1 = (size_t)1024 * 1024;
  dim3 blk(256);
  dim3 ablk(128);

  if (ws_size >= (size_t)64 * 1024 * 1024 + 16) {
    bf16_t* qb = wsb;
    bf16_t* kb = qb + M4;
    bf16_t* vb = kb + M4;
    bf16_t* wqb = vb + M4;
    bf16_t* wkb = wqb + M1;
    bf16_t* wvb = wkb + M1;
    bf16_t* wob = wvb + M1;
    bf16_t* qp = wob + M1;
    bf16_t* kp = qp + M4;
    bf16_t* vt = kp + M4;
    bf16_t* xp = vt + M4;
    convert_kernel<<<dim3(2048, 7), blk, 0, stream>>>(
        d_in[0], d_in[1], d_in[2], d_in[4], d_in[5], d_in[6], d_in[7], wsb,
        flag);
    qkv_fast<<<dim3(32, 8, 3), blk, 0, stream>>>(qb, kb, vb, wqb, wkb, wvb,
                                                 qp, kp, vt);
    attn_kernel<<<dim3(1024), ablk, 0, stream>>>(qp, kp, vt, xp);
    outproj_fast<<<dim3(32, 16), blk, 0, stream>>>(xp, wob, d_out, flag);
  } else {
    bf16_t* qws = wsb;
    bf16_t* kws = qws + M4;
    bf16_t* vws = kws + M4;
    bf16_t* xws = vws + M4;
    detect_kernel<<<1, blk, 0, stream>>>((const float*)d_in[0], flag);
    qkv_kernel<<<dim3(8, 32, 3), blk, 0, stream>>>(
        d_in[0], d_in[1], d_in[2], d_in[4], d_in[5], d_in[6], qws, kws, vws,
        flag);
    attn_kernel<<<dim3(1024), ablk, 0, stream>>>(qws, kws, vws, xws);
    outproj_kernel<<<dim3(8, 32), blk, 0, stream>>>(xws, d_in[7], d_out, flag);
  }
}

// Round 9
// 241.349 us; speedup vs baseline: 1.3117x; 1.3117x over previous
//
#include <hip/hip_runtime.h>
#include <hip/hip_bf16.h>

// MHA block: B=2, S=2048, D=1024, H=16, Dk=64. fp32 inputs (runtime-detected),
// bf16 MFMA with fp32 accumulation.
// Fast path (ws >= 64MiB+16): convert (fused dtype-detect) -> BK=64 GEMMs
// (global_load_lds + XOR chunk swizzle; XCD-local grid order) -> attn -> proj.
// Attention v6: round-6 v3 structure (LDS + global_load_lds staging, XOR
// swizzles, 0 bank conflicts, S^T=K.Q^T with key-permuted rows so P exits
// QK^T in PV A-fragment layout, denom via MFMA-ones) with TK=64 tiles (two
// 32-key halves per buffer -> half the barriers) and v5's XCD-local block
// mapping (bh = bx&31: all q-tiles of one head on one XCD's L2 -> 12 MB fetch).
// Q pre-scaled by 0.125*log2(e) -> raw v_exp_f32.

typedef __bf16 bf16_t;
typedef bf16_t bf16x8 __attribute__((ext_vector_type(8)));
typedef bf16_t bf16x4 __attribute__((ext_vector_type(4)));
typedef float f32x4 __attribute__((ext_vector_type(4)));

#define D_MODEL 1024
#define SEQ 2048
#define NH 16
#define DK 64

#define QSCALE 0.18033688011112042f  // 0.125 * log2(e)

__device__ __forceinline__ float fast_exp2(float x) {
#if __has_builtin(__builtin_amdgcn_exp2f)
  return __builtin_amdgcn_exp2f(x);
#else
  return exp2f(x);
#endif
}

// load 8 consecutive elements as bf16x8, converting from fp32 if f32 != 0.
__device__ __forceinline__ bf16x8 load8(const void* __restrict__ base,
                                        size_t idx, int f32) {
  if (f32) {
    f32x4 a = *(const f32x4*)((const float*)base + idx);
    f32x4 b = *(const f32x4*)((const float*)base + idx + 4);
    bf16x8 r;
    r[0] = (bf16_t)a[0]; r[1] = (bf16_t)a[1];
    r[2] = (bf16_t)a[2]; r[3] = (bf16_t)a[3];
    r[4] = (bf16_t)b[0]; r[5] = (bf16_t)b[1];
    r[6] = (bf16_t)b[2]; r[7] = (bf16_t)b[3];
    return r;
  }
  return *(const bf16x8*)((const bf16_t*)base + idx);
}

// ---------------------------------------------------------------------------
// standalone detector (fallback path only)
// ---------------------------------------------------------------------------
__global__ __launch_bounds__(256) void detect_kernel(const float* __restrict__ q,
                                                     int* __restrict__ flag) {
  __shared__ int total;
  if (threadIdx.x == 0) total = 0;
  __syncthreads();
  f32x4 v = ((const f32x4*)q)[threadIdx.x];
  int cnt = 0;
#pragma unroll
  for (int j = 0; j < 4; ++j) {
    unsigned u = __float_as_uint(v[j]);
    unsigned e = (u >> 23) & 0xffu;
    cnt += (e >= 0x70u && e <= 0x8fu) ? 1 : 0;
  }
  atomicAdd(&total, cnt);
  __syncthreads();
  if (threadIdx.x == 0) *flag = (total >= 512) ? 1 : 0;
}

// ---------------------------------------------------------------------------
// convert pass with fused per-block dtype detection.
// ---------------------------------------------------------------------------
__global__ __launch_bounds__(256) void convert_kernel(
    const void* __restrict__ s0, const void* __restrict__ s1,
    const void* __restrict__ s2, const void* __restrict__ s3,
    const void* __restrict__ s4, const void* __restrict__ s5,
    const void* __restrict__ s6, bf16_t* __restrict__ dst,
    int* __restrict__ flag_out) {
  const int t = blockIdx.y;
  const void* src = (t == 0) ? s0 : (t == 1) ? s1 : (t == 2) ? s2
                   : (t == 3) ? s3 : (t == 4) ? s4 : (t == 5) ? s5 : s6;
  const size_t sz = (t < 3) ? ((size_t)1 << 22) : ((size_t)1 << 20);
  const size_t off =
      (t < 3) ? ((size_t)t << 22) : ((size_t)12 << 20) + ((size_t)(t - 3) << 20);
  const size_t i = ((size_t)blockIdx.x * 256 + threadIdx.x) * 8;
  if (i >= sz) return;

  __shared__ int total;
  if (threadIdx.x == 0) total = 0;
  __syncthreads();
  const size_t wi = (i >> 1) & ~(size_t)3;
  f32x4 smp = *(const f32x4*)((const float*)src + wi);
  int cnt = 0;
#pragma unroll
  for (int j = 0; j < 4; ++j) {
    unsigned u = __float_as_uint(smp[j]);
    unsigned e = (u >> 23) & 0xffu;
    cnt += (e >= 0x70u && e <= 0x8fu) ? 1 : 0;
  }
  atomicAdd(&total, cnt);
  __syncthreads();
  const int f32 = (total >= 512) ? 1 : 0;
  if (t == 0 && blockIdx.x == 0 && threadIdx.x == 0) *flag_out = f32;

  *(bf16x8*)&dst[off + i] = load8(src, i, f32);
}

// ---------------------------------------------------------------------------
// async global(bf16)->LDS, 16B per lane; LDS dest = wave-uniform base+lane*16.
// ---------------------------------------------------------------------------
__device__ __forceinline__ void gload16(const bf16_t* g, bf16_t* l) {
  __builtin_amdgcn_global_load_lds(
      (const __attribute__((address_space(1))) unsigned int*)g,
      (__attribute__((address_space(3))) unsigned int*)l, 16, 0, 0);
}

// ---------------------------------------------------------------------------
// shared epilogue for C = A . W^T GEMMs (tile 128 x BN).
// ---------------------------------------------------------------------------
template <int NT>
__device__ __forceinline__ void gemm_epilogue(f32x4 acc[4][NT], void* out,
                                              int mode, int f32out, float osc,
                                              int m0, int n0, int wm, int wn,
                                              int l16, int quad) {
#pragma unroll
  for (int mt = 0; mt < 4; ++mt) {
#pragma unroll
    for (int nt = 0; nt < NT; ++nt) {
      const int mbase = m0 + wm + mt * 16 + quad * 4;
      const int n = n0 + wn + nt * 16 + l16;
      const int b = mbase >> 11;
      const int sbase = mbase & 2047;
      if (mode == 2) {
        const int h = n >> 6, d = n & 63;
        bf16x4 pk;
#pragma unroll
        for (int r = 0; r < 4; ++r) pk[r] = (bf16_t)acc[mt][nt][r];
        *(bf16x4*)&((bf16_t*)out)[((size_t)(b * NH + h) * DK + d) * SEQ +
                                  sbase] = pk;
      } else if (mode == 3) {
        if (f32out) {
#pragma unroll
          for (int r = 0; r < 4; ++r)
            ((float*)out)[(size_t)(mbase + r) * 1024 + n] = acc[mt][nt][r];
        } else {
#pragma unroll
          for (int r = 0; r < 4; ++r)
            ((bf16_t*)out)[(size_t)(mbase + r) * 1024 + n] =
                (bf16_t)acc[mt][nt][r];
        }
      } else {
        const int h = n >> 6, d = n & 63;
#pragma unroll
        for (int r = 0; r < 4; ++r)
          ((bf16_t*)out)[((size_t)(b * NH + h) * SEQ + (sbase + r)) * DK + d] =
              (bf16_t)(acc[mt][nt][r] * osc);
      }
    }
  }
}

// ---------------------------------------------------------------------------
// FAST GEMM: BK=64, global_load_lds staging with XOR chunk swizzle.
// m0/n0 passed in so callers pick grid order (m-tiles in fast dim -> all
// n-siblings sharing an A-tile land on one XCD: A fetched once per XCD).
// ---------------------------------------------------------------------------
template <int BN>
__device__ __forceinline__ void gemm_fast_body(const bf16_t* __restrict__ A,
                                               const bf16_t* __restrict__ W,
                                               void* __restrict__ out, int mode,
                                               int f32out, float osc, int m0,
                                               int n0) {
  constexpr int NT = BN / 32;
  constexpr int BR = BN / 32;
  __shared__ alignas(16) bf16_t lA[128 * 64];
  __shared__ alignas(16) bf16_t lB[BN * 64];
  const int tid = threadIdx.x;
  const int ln = tid & 63;
  const int wave = tid >> 6;
  const int l16 = ln & 15;
  const int quad = ln >> 4;
  const int wm = (wave & 1) * 64;
  const int wn = (wave >> 1) * (BN / 2);
  f32x4 acc[4][NT] = {};

  const int srow = ln >> 3;
  const int schunk = ((ln & 7) ^ (ln >> 3)) * 8;
  const int pc0 = (quad ^ (l16 & 7)) * 8;
  const int pc1 = ((quad + 4) ^ (l16 & 7)) * 8;

  for (int k0 = 0; k0 < 1024; k0 += 64) {
    __syncthreads();
#pragma unroll
    for (int i = 0; i < 4; ++i)
      gload16(&A[(size_t)(m0 + i * 32 + wave * 8 + srow) * 1024 + k0 + schunk],
              &lA[i * 2048 + wave * 512]);
#pragma unroll
    for (int i = 0; i < BR; ++i)
      gload16(&W[(size_t)(n0 + i * 32 + wave * 8 + srow) * 1024 + k0 + schunk],
              &lB[i * 2048 + wave * 512]);
    __syncthreads();

    bf16x8 af0[4], af1[4], bf0[NT], bf1[NT];
#pragma unroll
    for (int mt = 0; mt < 4; ++mt) {
      af0[mt] = *(bf16x8*)&lA[(wm + mt * 16 + l16) * 64 + pc0];
      af1[mt] = *(bf16x8*)&lA[(wm + mt * 16 + l16) * 64 + pc1];
    }
#pragma unroll
    for (int nt = 0; nt < NT; ++nt) {
      bf0[nt] = *(bf16x8*)&lB[(wn + nt * 16 + l16) * 64 + pc0];
      bf1[nt] = *(bf16x8*)&lB[(wn + nt * 16 + l16) * 64 + pc1];
    }
#pragma unroll
    for (int mt = 0; mt < 4; ++mt)
#pragma unroll
      for (int nt = 0; nt < NT; ++nt) {
        acc[mt][nt] = __builtin_amdgcn_mfma_f32_16x16x32_bf16(
            af0[mt], bf0[nt], acc[mt][nt], 0, 0, 0);
        acc[mt][nt] = __builtin_amdgcn_mfma_f32_16x16x32_bf16(
            af1[mt], bf1[nt], acc[mt][nt], 0, 0, 0);
      }
  }
  gemm_epilogue<NT>(acc, out, mode, f32out, osc, m0, n0, wm, wn, l16, quad);
}

__global__ __launch_bounds__(256) void qkv_fast(
    const bf16_t* __restrict__ qb, const bf16_t* __restrict__ kb,
    const bf16_t* __restrict__ vb, const bf16_t* __restrict__ wqb,
    const bf16_t* __restrict__ wkb, const bf16_t* __restrict__ wvb,
    bf16_t* __restrict__ qo, bf16_t* __restrict__ ko, bf16_t* __restrict__ vo) {
  const int z = blockIdx.z;
  const bf16_t* A = (z == 0) ? qb : (z == 1) ? kb : vb;
  const bf16_t* W = (z == 0) ? wqb : (z == 1) ? wkb : wvb;
  bf16_t* O = (z == 0) ? qo : (z == 1) ? ko : vo;
  gemm_fast_body<128>(A, W, O, (z == 2) ? 2 : 0, 0, (z == 0) ? QSCALE : 1.0f,
                      blockIdx.x * 128, blockIdx.y * 128);
}

__global__ __launch_bounds__(256) void outproj_fast(
    const bf16_t* __restrict__ X, const bf16_t* __restrict__ wob,
    void* __restrict__ out, const int* __restrict__ flag) {
  gemm_fast_body<64>(X, wob, out, 3, *flag, 1.0f, blockIdx.x * 128,
                     blockIdx.y * 64);
}

// ---------------------------------------------------------------------------
// FALLBACK GEMM: fused fp32->bf16 staging through VGPRs (BK=32).
// ---------------------------------------------------------------------------
__device__ __forceinline__ void gemm_bt_body(const void* __restrict__ A,
                                             const void* __restrict__ W,
                                             void* __restrict__ out, int mode,
                                             int aRaw, float osc,
                                             const int* __restrict__ flag) {
  __shared__ alignas(16) bf16_t lA[128 * 32];
  __shared__ alignas(16) bf16_t lB[128 * 32];
  const int f = *flag;
  const int af32 = aRaw ? f : 0;

  const int tid = threadIdx.x;
  const int lane = tid & 63;
  const int wave = tid >> 6;
  const int l16 = lane & 15;
  const int quad = lane >> 4;
  const int m0 = blockIdx.y * 128;
  const int n0 = blockIdx.x * 128;
  const int wm = (wave & 1) * 64;
  const int wn = (wave >> 1) * 64;

  f32x4 acc[4][4] = {};
  const int r0 = tid >> 2;
  const int kc = (tid & 3) * 8;

  for (int k0 = 0; k0 < 1024; k0 += 32) {
    __syncthreads();
    *(bf16x8*)&lA[r0 * 32 + kc] =
        load8(A, (size_t)(m0 + r0) * 1024 + k0 + kc, af32);
    *(bf16x8*)&lA[(r0 + 64) * 32 + kc] =
        load8(A, (size_t)(m0 + r0 + 64) * 1024 + k0 + kc, af32);
    *(bf16x8*)&lB[r0 * 32 + kc] =
        load8(W, (size_t)(n0 + r0) * 1024 + k0 + kc, f);
    *(bf16x8*)&lB[(r0 + 64) * 32 + kc] =
        load8(W, (size_t)(n0 + r0 + 64) * 1024 + k0 + kc, f);
    __syncthreads();

    bf16x8 af[4], bfr[4];
#pragma unroll
    for (int mt = 0; mt < 4; ++mt)
      af[mt] = *(bf16x8*)&lA[(wm + mt * 16 + l16) * 32 + quad * 8];
#pragma unroll
    for (int nt = 0; nt < 4; ++nt)
      bfr[nt] = *(bf16x8*)&lB[(wn + nt * 16 + l16) * 32 + quad * 8];
#pragma unroll
    for (int mt = 0; mt < 4; ++mt)
#pragma unroll
      for (int nt = 0; nt < 4; ++nt)
        acc[mt][nt] = __builtin_amdgcn_mfma_f32_16x16x32_bf16(
            af[mt], bfr[nt], acc[mt][nt], 0, 0, 0);
  }
  gemm_epilogue<4>(acc, out, mode, (mode == 3) ? f : 0, osc, m0, n0, wm, wn,
                   l16, quad);
}

__global__ __launch_bounds__(256) void qkv_kernel(
    const void* __restrict__ q, const void* __restrict__ k,
    const void* __restrict__ v, const void* __restrict__ wq,
    const void* __restrict__ wk, const void* __restrict__ wv,
    bf16_t* __restrict__ qo, bf16_t* __restrict__ ko, bf16_t* __restrict__ vo,
    const int* __restrict__ flag) {
  const int z = blockIdx.z;
  const void* A = (z == 0) ? q : (z == 1) ? k : v;
  const void* W = (z == 0) ? wq : (z == 1) ? wk : wv;
  bf16_t* O = (z == 0) ? qo : (z == 1) ? ko : vo;
  gemm_bt_body(A, W, O, (z == 2) ? 2 : 0, 1, (z == 0) ? QSCALE : 1.0f, flag);
}

__global__ __launch_bounds__(256) void outproj_kernel(
    const bf16_t* __restrict__ X, const void* __restrict__ wo,
    void* __restrict__ out, const int* __restrict__ flag) {
  gemm_bt_body(X, wo, out, 3, 0, 1.0f, flag);
}

// ---------------------------------------------------------------------------
// Attention v6: 512 blocks x 256 threads; block = (b,h) x 128 q-rows; wave =
// 32 q-rows (2 m-subtiles share K/V frags). TK=64 key tiles as two 32-key
// halves per buffer (half the barriers of v3), unpadded LDS, global_load_lds
// staging with key-permuted rows + XOR chunk swizzle (0 conflicts, verified
// round 6). XCD-local mapping: bh = bx&31 -> all q-tiles of one head on one
// XCD's L2 (12 MB fetch, verified round 8).
// ---------------------------------------------------------------------------
#define ATTN_STAGE(BUF, TILE)                                     \
  {                                                               \
    const size_t ko_ = (size_t)(TILE)*4096;                       \
    const size_t vo_ = (size_t)(TILE)*64;                         \
    gload16(kgp + ko_, kldA##BUF);                                \
    gload16(kgp + ko_ + 2048, kldB##BUF);                         \
    gload16(vgp + vo_, vldA##BUF);                                \
    gload16(vgp + vo_ + 32, vldB##BUF);                           \
  }

#define ATTN_COMPUTE(BUF, HOFF)                                              \
  {                                                                          \
    const bf16_t* lKb = &lK[BUF][HOFF];                                      \
    const bf16_t* lVb = &lV[BUF][HOFF];                                      \
    float pv0[8], pv1[8];                                                    \
    _Pragma("unroll") for (int nt = 0; nt < 2; ++nt) {                       \
      const int krow = nt * 16 + l16;                                        \
      bf16x8 kf0 = *(bf16x8*)&lKb[krow * 64 + kc0 * 8];                      \
      bf16x8 kf1 = *(bf16x8*)&lKb[krow * 64 + kc1 * 8];                      \
      f32x4 s0 = {0.f, 0.f, 0.f, 0.f};                                       \
      f32x4 s1 = {0.f, 0.f, 0.f, 0.f};                                       \
      s0 = __builtin_amdgcn_mfma_f32_16x16x32_bf16(kf0, qf00, s0, 0, 0, 0);  \
      s0 = __builtin_amdgcn_mfma_f32_16x16x32_bf16(kf1, qf01, s0, 0, 0, 0);  \
      s1 = __builtin_amdgcn_mfma_f32_16x16x32_bf16(kf0, qf10, s1, 0, 0, 0);  \
      s1 = __builtin_amdgcn_mfma_f32_16x16x32_bf16(kf1, qf11, s1, 0, 0, 0);  \
      _Pragma("unroll") for (int r = 0; r < 4; ++r) {                        \
        pv0[nt * 4 + r] = fast_exp2(s0[r]);                                  \
        pv1[nt * 4 + r] = fast_exp2(s1[r]);                                  \
      }                                                                      \
    }                                                                        \
    bf16x8 pf0, pf1;                                                         \
    _Pragma("unroll") for (int j = 0; j < 8; ++j) {                          \
      pf0[j] = (bf16_t)pv0[j];                                               \
      pf1[j] = (bf16_t)pv1[j];                                               \
    }                                                                        \
    sacc0 = __builtin_amdgcn_mfma_f32_16x16x32_bf16(pf0, ones, sacc0, 0, 0, 0); \
    sacc1 = __builtin_amdgcn_mfma_f32_16x16x32_bf16(pf1, ones, sacc1, 0, 0, 0); \
    _Pragma("unroll") for (int ntd = 0; ntd < 4; ++ntd) {                    \
      bf16x8 vf = *(bf16x8*)&lVb[(ntd * 16 + l16) * 32 + vc0 * 8];           \
      xacc0[ntd] = __builtin_amdgcn_mfma_f32_16x16x32_bf16(pf0, vf,          \
                                                           xacc0[ntd], 0, 0, 0); \
      xacc1[ntd] = __builtin_amdgcn_mfma_f32_16x16x32_bf16(pf1, vf,          \
                                                           xacc1[ntd], 0, 0, 0); \
    }                                                                        \
  }

__global__ __launch_bounds__(256) void attn_kernel(
    const bf16_t* __restrict__ qws, const bf16_t* __restrict__ kws,
    const bf16_t* __restrict__ vtws, bf16_t* __restrict__ xws) {
  const int tid = threadIdx.x;
  const int lane = tid & 63;
  const int wave = tid >> 6;
  const int l16 = lane & 15;
  const int quad = lane >> 4;
  const int bx = blockIdx.x;
  const int bh = bx & 31;  // XCD-local: bx%8 fixed per head
  const int qt = bx >> 5;  // 128-row q block (0..15)
  const int b = bh >> 4, h = bh & 15;

  const bf16_t* qp = qws + (size_t)bh * SEQ * DK;
  const bf16_t* kp = kws + (size_t)bh * SEQ * DK;
  const bf16_t* vp = vtws + (size_t)bh * DK * SEQ;
  const int qrow = qt * 128 + wave * 32;

  __shared__ alignas(16) bf16_t lK[2][64 * 64];  // 2 halves x 32x64 each
  __shared__ alignas(16) bf16_t lV[2][64 * 64];  // 2 halves x 64x32 each

  // Q fragments: 2 m-subtiles x 2 dk-halves, held for the whole loop
  const bf16x8 qf00 = *(const bf16x8*)&qp[(size_t)(qrow + l16) * DK + quad * 8];
  const bf16x8 qf01 =
      *(const bf16x8*)&qp[(size_t)(qrow + l16) * DK + 32 + quad * 8];
  const bf16x8 qf10 =
      *(const bf16x8*)&qp[(size_t)(qrow + 16 + l16) * DK + quad * 8];
  const bf16x8 qf11 =
      *(const bf16x8*)&qp[(size_t)(qrow + 16 + l16) * DK + 32 + quad * 8];

  // K staging (per 32-key half, round-6 layout): row km, chunk XOR swizzle,
  // inverse key permutation baked into the global address.
  const int km = wave * 8 + (lane >> 3);
  const int kc = (lane & 7) ^ (km & 7);
  const int kkey = ((km & 15) >> 2) * 8 + (km >> 4) * 4 + (km & 3);
  const bf16_t* kgp = kp + (size_t)kkey * DK + kc * 8;
  bf16_t* kldA0 = &lK[0][wave * 512];
  bf16_t* kldB0 = &lK[0][2048 + wave * 512];
  bf16_t* kldA1 = &lK[1][wave * 512];
  bf16_t* kldB1 = &lK[1][2048 + wave * 512];

  // V staging (per half): row vrow, XOR chunk swizzle.
  const int vrow = wave * 16 + (lane >> 2);
  const int vc = (lane & 3) ^ ((vrow >> 1) & 3);
  const bf16_t* vgp = vp + (size_t)vrow * SEQ + vc * 8;
  bf16_t* vldA0 = &lV[0][wave * 512];
  bf16_t* vldB0 = &lV[0][2048 + wave * 512];
  bf16_t* vldA1 = &lV[1][wave * 512];
  bf16_t* vldB1 = &lV[1][2048 + wave * 512];

  // fragment-read swizzled chunk indices (loop-invariant)
  const int kc0 = quad ^ (l16 & 7);
  const int kc1 = (quad + 4) ^ (l16 & 7);
  const int vc0 = quad ^ ((l16 >> 1) & 3);

  bf16x8 ones;
#pragma unroll
  for (int j = 0; j < 8; ++j) ones[j] = (bf16_t)1.0f;

  f32x4 xacc0[4] = {}, xacc1[4] = {};
  f32x4 sacc0 = {0.f, 0.f, 0.f, 0.f};
  f32x4 sacc1 = {0.f, 0.f, 0.f, 0.f};

  ATTN_STAGE(0, 0);
  __syncthreads();

  for (int t = 0; t < 32; t += 2) {
    ATTN_STAGE(1, t + 1);
    ATTN_COMPUTE(0, 0);
    ATTN_COMPUTE(0, 2048);
    __syncthreads();
    if (t < 30) ATTN_STAGE(0, t + 2);
    ATTN_COMPUTE(1, 0);
    ATTN_COMPUTE(1, 2048);
    __syncthreads();
  }

  float li0[4], li1[4];
#pragma unroll
  for (int r = 0; r < 4; ++r) {
    li0[r] = 1.0f / sacc0[r];
    li1[r] = 1.0f / sacc1[r];
  }

#pragma unroll
  for (int ntd = 0; ntd < 4; ++ntd)
#pragma unroll
    for (int r = 0; r < 4; ++r) {
      const int col = h * DK + ntd * 16 + l16;
      const int s0 = qrow + quad * 4 + r;
      const int s1 = qrow + 16 + quad * 4 + r;
      xws[((size_t)b * SEQ + s0) * D_MODEL + col] =
          (bf16_t)(xacc0[ntd][r] * li0[r]);
      xws[((size_t)b * SEQ + s1) * D_MODEL + col] =
          (bf16_t)(xacc1[ntd][r] * li1[r]);
    }
}

extern "C" void kernel_launch(void* const* d_in, const int* in_sizes, int n_in,
                              void* d_out, int out_size, void* d_ws,
                              size_t ws_size, hipStream_t stream) {
  char* base = (char*)d_ws;
  int* flag = (int*)base;
  bf16_t* wsb = (bf16_t*)(base + 16);
  const size_t M4 = (size_t)4 * 1024 * 1024;
  const size_t M1 = (size_t)1024 * 1024;
  dim3 blk(256);

  if (ws_size >= (size_t)64 * 1024 * 1024 + 16) {
    bf16_t* qb = wsb;
    bf16_t* kb = qb + M4;
    bf16_t* vb = kb + M4;
    bf16_t* wqb = vb + M4;
    bf16_t* wkb = wqb + M1;
    bf16_t* wvb = wkb + M1;
    bf16_t* wob = wvb + M1;
    bf16_t* qp = wob + M1;
    bf16_t* kp = qp + M4;
    bf16_t* vt = kp + M4;
    bf16_t* xp = vt + M4;
    convert_kernel<<<dim3(2048, 7), blk, 0, stream>>>(
        d_in[0], d_in[1], d_in[2], d_in[4], d_in[5], d_in[6], d_in[7], wsb,
        flag);
    qkv_fast<<<dim3(32, 8, 3), blk, 0, stream>>>(qb, kb, vb, wqb, wkb, wvb,
                                                 qp, kp, vt);
    attn_kernel<<<dim3(512), blk, 0, stream>>>(qp, kp, vt, xp);
    outproj_fast<<<dim3(32, 16), blk, 0, stream>>>(xp, wob, d_out, flag);
  } else {
    bf16_t* qws = wsb;
    bf16_t* kws = qws + M4;
    bf16_t* vws = kws + M4;
    bf16_t* xws = vws + M4;
    detect_kernel<<<1, blk, 0, stream>>>((const float*)d_in[0], flag);
    qkv_kernel<<<dim3(8, 32, 3), blk, 0, stream>>>(
        d_in[0], d_in[1], d_in[2], d_in[4], d_in[5], d_in[6], qws, kws, vws,
        flag);
    attn_kernel<<<dim3(512), blk, 0, stream>>>(qws, kws, vws, xws);
    outproj_kernel<<<dim3(8, 32), blk, 0, stream>>>(xws, d_in[7], d_out, flag);
  }
}